// Round 4
// baseline (36.155 us; speedup 1.0000x reference)
//
#include <hip/hip_runtime.h>
#include <math.h>

// Volume rendering: R rays, N=192 samples/ray.
// One wavefront per ray-iteration; lane l owns contiguous samples {3l,3l+1,3l+2}.
// Persistent waves (8 rays each) with 1-deep software-pipelined prefetch:
// ray i+1's loads are issued before ray i's shuffle-scan, keeping VMEM busy
// under the serial scan chain.

constexpr int N_SAMP = 192;  // == 3 * 64
constexpr float EPS = 1e-10f;

__device__ __forceinline__ void load_ray(const float* __restrict__ dens,
                                         const float* __restrict__ rgbs,
                                         int ray, int lane,
                                         float dv[3], float r[9]) {
    const float* __restrict__ dp = dens + (size_t)ray * N_SAMP + 3 * lane;
    const float* __restrict__ rp = rgbs + ((size_t)ray * N_SAMP + 3 * lane) * 3;
#pragma unroll
    for (int i = 0; i < 3; ++i) dv[i] = dp[i];
#pragma unroll
    for (int i = 0; i < 9; ++i) r[i] = rp[i];
}

__device__ __forceinline__ void compute_ray(int ray, int lane, float delta,
                                            const float dv[3], const float r[9],
                                            float* __restrict__ out) {
    float a[3], t[3];
#pragma unroll
    for (int i = 0; i < 3; ++i) {
        a[i] = 1.0f - __expf(-dv[i] * delta);
        t[i] = 1.0f - a[i] + EPS;
    }

    // wave-wide exclusive product scan over lane-local products
    float incl = t[0] * t[1] * t[2];
#pragma unroll
    for (int off = 1; off < 64; off <<= 1) {
        const float up = __shfl_up(incl, off, 64);
        incl *= (lane >= off) ? up : 1.0f;
    }
    float excl = __shfl_up(incl, 1, 64);
    if (lane == 0) excl = 1.0f;

    const float w0 = excl * a[0];
    const float e1 = excl * t[0];
    const float w1 = e1 * a[1];
    const float w2 = e1 * t[1] * a[2];

    float sr = w0 * r[0] + w1 * r[3] + w2 * r[6];
    float sg = w0 * r[1] + w1 * r[4] + w2 * r[7];
    float sb = w0 * r[2] + w1 * r[5] + w2 * r[8];

#pragma unroll
    for (int off = 32; off >= 1; off >>= 1) {
        sr += __shfl_down(sr, off, 64);
        sg += __shfl_down(sg, off, 64);
        sb += __shfl_down(sb, off, 64);
    }
    if (lane == 0) {
        float* o = out + (size_t)ray * 3;
        o[0] = sr;
        o[1] = sg;
        o[2] = sb;
    }
}

__global__ __launch_bounds__(256) void render_kernel(
    const float* __restrict__ rgbs,   // (R, N, 3)
    const float* __restrict__ dens,   // (R, N)
    const float* __restrict__ pts,    // (R, N, 3) -- only first 6 floats used
    float* __restrict__ out,          // (R, 3)
    int R)
{
    const int lane   = threadIdx.x & 63;
    const int wave   = (blockIdx.x * blockDim.x + threadIdx.x) >> 6;
    const int nwaves = (gridDim.x * blockDim.x) >> 6;

    // delta: scalar step size from ray 0, samples 0 and 1 (uniform address)
    const float dx = pts[3] - pts[0];
    const float dy = pts[4] - pts[1];
    const float dz = pts[5] - pts[2];
    const float delta = sqrtf(dx * dx + dy * dy + dz * dz);

    int ray = wave;
    if (ray >= R) return;

    float dv[3], r[9];
    load_ray(dens, rgbs, ray, lane, dv, r);

    for (;;) {
        const int next = ray + nwaves;        // wave-uniform branch
        float dv2[3], r2[9];
        if (next < R) load_ray(dens, rgbs, next, lane, dv2, r2);  // prefetch
        compute_ray(ray, lane, delta, dv, r, out);
        if (next >= R) break;
#pragma unroll
        for (int i = 0; i < 3; ++i) dv[i] = dv2[i];
#pragma unroll
        for (int i = 0; i < 9; ++i) r[i] = r2[i];
        ray = next;
    }
}

extern "C" void kernel_launch(void* const* d_in, const int* in_sizes, int n_in,
                              void* d_out, int out_size, void* d_ws, size_t ws_size,
                              hipStream_t stream) {
    const float* rgbs = (const float*)d_in[0];
    const float* dens = (const float*)d_in[1];
    const float* pts  = (const float*)d_in[2];
    float* out = (float*)d_out;

    const int R = in_sizes[1] / N_SAMP;  // densities is (R, N)

    // persistent waves: 2048 blocks x 4 waves = 8192 waves -> 8 rays/wave
    dim3 block(256);
    int nblocks = 2048;
    const int max_blocks = (R + 3) / 4;   // never more than 1 ray per wave
    if (nblocks > max_blocks) nblocks = max_blocks;
    render_kernel<<<dim3(nblocks), block, 0, stream>>>(rgbs, dens, pts, out, R);
}

// Round 5
// 34.578 us; speedup vs baseline: 1.0456x; 1.0456x over previous
//
#include <hip/hip_runtime.h>
#include <math.h>

// Volume rendering: R rays, N=192 samples/ray.
// One wavefront per ray; lanes 0..47 each own 4 CONTIGUOUS samples
// {4l..4l+3}: rgb = 48B = 3 aligned float4 loads, density = 1 aligned float4.
// Lanes 48..63 idle (memory-bound; wave footprint stays fully contiguous).
// Single 64-lane exclusive product scan (idle lanes hold 1.0), no carry.

constexpr int N_SAMP = 192;  // == 48 * 4
constexpr float EPS = 1e-10f;

__global__ __launch_bounds__(256) void render_kernel(
    const float* __restrict__ rgbs,   // (R, N, 3)
    const float* __restrict__ dens,   // (R, N)
    const float* __restrict__ pts,    // (R, N, 3) -- only first 6 floats used
    float* __restrict__ out,          // (R, 3)
    int R)
{
    const int lane = threadIdx.x & 63;
    const int ray  = (blockIdx.x * blockDim.x + threadIdx.x) >> 6;
    if (ray >= R) return;

    // delta: scalar step size from ray 0, samples 0 and 1 (uniform address)
    const float dx = pts[3] - pts[0];
    const float dy = pts[4] - pts[1];
    const float dz = pts[5] - pts[2];
    const float delta = sqrtf(dx * dx + dy * dy + dz * dz);

    const bool active = lane < 48;

    float4 dv = make_float4(0.f, 0.f, 0.f, 0.f);
    float4 c0 = dv, c1 = dv, c2 = dv;   // 12 rgb floats of the 4 owned samples
    if (active) {
        // density: ray*768B + lane*16B, 16B-aligned
        dv = *reinterpret_cast<const float4*>(dens + (size_t)ray * N_SAMP + 4 * lane);
        // rgb: ray*2304B + lane*48B, 16B-aligned; 3 x float4
        const float4* rp4 =
            reinterpret_cast<const float4*>(rgbs + ((size_t)ray * N_SAMP + 4 * lane) * 3);
        c0 = rp4[0];
        c1 = rp4[1];
        c2 = rp4[2];
    }

    // alpha / transmittance factors for the 4 owned samples
    float a0 = 1.0f - __expf(-dv.x * delta);
    float a1 = 1.0f - __expf(-dv.y * delta);
    float a2 = 1.0f - __expf(-dv.z * delta);
    float a3 = 1.0f - __expf(-dv.w * delta);
    float t0 = 1.0f - a0 + EPS;
    float t1 = 1.0f - a1 + EPS;
    float t2 = 1.0f - a2 + EPS;
    float t3 = 1.0f - a3 + EPS;

    // wave-wide exclusive product scan over lane-local products
    float incl = active ? (t0 * t1) * (t2 * t3) : 1.0f;
#pragma unroll
    for (int off = 1; off < 64; off <<= 1) {
        const float up = __shfl_up(incl, off, 64);
        incl *= (lane >= off) ? up : 1.0f;
    }
    float excl = __shfl_up(incl, 1, 64);   // prod of all samples before 4*lane
    if (lane == 0) excl = 1.0f;

    // in-lane exclusive terms and weights
    const float w0 = excl * a0;
    const float e1 = excl * t0;
    const float w1 = e1 * a1;
    const float e2 = e1 * t1;
    const float w2 = e2 * a2;
    const float w3 = e2 * t2 * a3;

    // weighted RGB accumulation, fully in-lane
    // sample0 rgb = (c0.x,c0.y,c0.z); s1 = (c0.w,c1.x,c1.y);
    // s2 = (c1.z,c1.w,c2.x);         s3 = (c2.y,c2.z,c2.w)
    float sr = w0 * c0.x + w1 * c0.w + w2 * c1.z + w3 * c2.y;
    float sg = w0 * c0.y + w1 * c1.x + w2 * c1.w + w3 * c2.z;
    float sb = w0 * c0.z + w1 * c1.y + w2 * c2.x + w3 * c2.w;

    // wave reduction of the three channel sums (idle lanes contribute 0)
#pragma unroll
    for (int off = 32; off >= 1; off >>= 1) {
        sr += __shfl_down(sr, off, 64);
        sg += __shfl_down(sg, off, 64);
        sb += __shfl_down(sb, off, 64);
    }
    if (lane == 0) {
        float* o = out + (size_t)ray * 3;
        o[0] = sr;
        o[1] = sg;
        o[2] = sb;
    }
}

extern "C" void kernel_launch(void* const* d_in, const int* in_sizes, int n_in,
                              void* d_out, int out_size, void* d_ws, size_t ws_size,
                              hipStream_t stream) {
    const float* rgbs = (const float*)d_in[0];
    const float* dens = (const float*)d_in[1];
    const float* pts  = (const float*)d_in[2];
    float* out = (float*)d_out;

    const int R = in_sizes[1] / N_SAMP;  // densities is (R, N)

    const int waves_per_block = 4;       // 256 threads
    dim3 block(256);
    dim3 grid((R + waves_per_block - 1) / waves_per_block);
    render_kernel<<<grid, block, 0, stream>>>(rgbs, dens, pts, out, R);
}